// Round 9
// baseline (207.482 us; speedup 1.0000x reference)
//
#include <hip/hip_runtime.h>

typedef __bf16 bf16;
typedef bf16 bf16x8 __attribute__((ext_vector_type(8)));
typedef float f32x4 __attribute__((ext_vector_type(4)));

#define PTS 16          // points per block (4 per wave)
#define WREG 4800       // per-wave LDS: 12 T-rows x 400B pitch (T ONLY)
// R9: minimum-phase kernel. One vmcnt drain, ONE barrier, no epilogue LDS.
//   burst-load J/X/W to regs -> terms -> T to LDS -> syncthreads -> MFMA
//   -> Y stored DIRECTLY from accumulators (posted stores, block retires).
// LDS 4*4800 = 19200 B. launch_bounds(256,4): VGPR cap 128, 4 blk/CU
// (occupancy beyond 3 blk/CU proven irrelevant, R1/R4/R8).

__global__ __launch_bounds__(256, 4)
void affine_linear_fused(const float* __restrict__ X, const float* __restrict__ J,
                         const float* __restrict__ A, const float* __restrict__ Bm,
                         const float* __restrict__ C, float* __restrict__ Y)
{
    __shared__ __attribute__((aligned(128))) unsigned char lds[4 * WREG];

    const int tid  = threadIdx.x;
    const int wave = tid >> 6;
    const int lane = tid & 63;
    const int l16  = lane & 15;
    const int lq   = lane >> 4;       // quad 0..3
    const long bn0 = (long)blockIdx.x * PTS;

    unsigned char* wbase = &lds[wave * WREG];

    // ---- Burst 1: J direct to regs (lane d owns its 24B of each point's J) ----
    float jv[4][6];
    {
        const float* jg = J + (bn0 + wave * 4) * 384 + lane * 6;
        #pragma unroll
        for (int q = 0; q < 4; ++q) {
            float2 ja  = *(const float2*)(jg + q * 384 + 0);
            float2 jb  = *(const float2*)(jg + q * 384 + 2);
            float2 jc2 = *(const float2*)(jg + q * 384 + 4);
            jv[q][0] = ja.x;  jv[q][1] = ja.y;
            jv[q][2] = jb.x;  jv[q][3] = jb.y;
            jv[q][4] = jc2.x; jv[q][5] = jc2.y;
        }
    }

    // ---- Burst 2: X direct (3 scalars per point) ----
    float xv[4][3];
    {
        const float* xg = X + (bn0 + wave * 4) * 192 + lane * 3;
        #pragma unroll
        for (int q = 0; q < 4; ++q) {
            xv[q][0] = xg[q * 192 + 0];
            xv[q][1] = xg[q * 192 + 1];
            xv[q][2] = xg[q * 192 + 2];
        }
    }

    // ---- Burst 3: W fragments (L2/L3-hot after first blocks) ----
    // W[f,k]: f = wave*16+l16; k = kk*32 + lq*8 + j; kk<2:A, <4:Bm, else C
    const int f = wave * 16 + l16;
    f32x4 wlo[6], whi[6];
    #pragma unroll
    for (int kk = 0; kk < 6; ++kk) {
        const float* src = (kk < 2) ? A : (kk < 4) ? Bm : C;
        const f32x4* p4 = (const f32x4*)(src + f * 64 + (kk & 1) * 32 + lq * 8);
        wlo[kk] = p4[0];
        whi[kk] = p4[1];
    }

    // ONE drain for everything.
    __asm__ volatile("s_waitcnt vmcnt(0)" ::: "memory");

    bf16x8 wfrag[6];
    #pragma unroll
    for (int kk = 0; kk < 6; ++kk) {
        bf16x8 w;
        w[0] = (bf16)wlo[kk][0]; w[1] = (bf16)wlo[kk][1];
        w[2] = (bf16)wlo[kk][2]; w[3] = (bf16)wlo[kk][3];
        w[4] = (bf16)whi[kk][0]; w[5] = (bf16)whi[kk][1];
        w[6] = (bf16)whi[kk][2]; w[7] = (bf16)whi[kk][3];
        wfrag[kk] = w;
    }

    // ---- Terms -> T rows (row = q*3+i at 400B pitch) ----
    #pragma unroll
    for (int q = 0; q < 4; ++q) {
        float a1x = jv[q][0], a2x = jv[q][1];
        float a1y = jv[q][2], a2y = jv[q][3];
        float a1z = jv[q][4], a2z = jv[q][5];
        float xx = xv[q][0], xy = xv[q][1], xz = xv[q][2];

        float n1sq = a1x*a1x + a1y*a1y + a1z*a1z;
        float inv1 = __builtin_amdgcn_rsqf(fmaxf(n1sq, 1e-24f));  // == 1/max(sqrt,1e-12)
        float b1x = a1x*inv1, b1y = a1y*inv1, b1z = a1z*inv1;
        float dot = b1x*a2x + b1y*a2y + b1z*a2z;
        float ux = a2x - dot*b1x, uy = a2y - dot*b1y, uz = a2z - dot*b1z;
        float n2sq = ux*ux + uy*uy + uz*uz;
        float inv2 = __builtin_amdgcn_rsqf(fmaxf(n2sq, 1e-24f));
        float b2x = ux*inv2, b2y = uy*inv2, b2z = uz*inv2;
        float b3x = b1y*b2z - b1z*b2y;
        float b3y = b1z*b2x - b1x*b2z;
        float b3z = b1x*b2y - b1y*b2x;

        float rt0 = b1x*xx + b1y*xy + b1z*xz;
        float rt1 = b2x*xx + b2y*xy + b2z*xz;
        float rt2 = b3x*xx + b3y*xy + b3z*xz;

        float at0 = b1x*rt0 + b2x*rt1;
        float at1 = b1y*rt0 + b2y*rt1;
        float at2 = b1z*rt0 + b2z*rt1;
        float bt0 = b2x*rt0 - b1x*rt1;
        float bt1 = b2y*rt0 - b1y*rt1;
        float bt2 = b2z*rt0 - b1z*rt1;
        float ct0 = b3x*rt2, ct1 = b3y*rt2, ct2 = b3z*rt2;

        bf16* r0 = (bf16*)(wbase + (q*3 + 0) * 400);
        bf16* r1 = (bf16*)(wbase + (q*3 + 1) * 400);
        bf16* r2 = (bf16*)(wbase + (q*3 + 2) * 400);
        r0[lane] = (bf16)at0; r0[64+lane] = (bf16)bt0; r0[128+lane] = (bf16)ct0;
        r1[lane] = (bf16)at1; r1[64+lane] = (bf16)bt1; r1[128+lane] = (bf16)ct1;
        r2[lane] = (bf16)at2; r2[64+lane] = (bf16)bt2; r2[128+lane] = (bf16)ct2;
    }

    __syncthreads();   // the ONLY barrier: publish T

    // ---- MFMA: D[m,f] = sum_k T[m,k] * W[f,k]; T row m = wv*12 + r ----
    const unsigned char* arow[3];
    #pragma unroll
    for (int mt = 0; mt < 3; ++mt) {
        int m  = mt * 16 + l16;
        int wv = m / 12;
        int r  = m - wv * 12;
        arow[mt] = &lds[wv * WREG + r * 400] + lq * 16;
    }
    f32x4 acc[3];
    #pragma unroll
    for (int mt = 0; mt < 3; ++mt) acc[mt] = (f32x4){0.f, 0.f, 0.f, 0.f};
    #pragma unroll
    for (int kk = 0; kk < 6; ++kk) {
        #pragma unroll
        for (int mt = 0; mt < 3; ++mt) {
            bf16x8 af = *(const bf16x8*)(arow[mt] + kk * 64);
            acc[mt] = __builtin_amdgcn_mfma_f32_16x16x32_bf16(af, wfrag[kk], acc[mt], 0, 0, 0);
        }
    }

    // ---- Y: store DIRECTLY from accumulators (posted; no barrier-2, no LDS).
    //      acc[mt][r] is D[m, f] with m = mt*16 + lq*4 + r, p = m/3, i = m%3;
    //      addr = (bn0 + p)*192 + f*3 + i ----
    float* yb = Y + (bn0) * 192 + f * 3;
    #pragma unroll
    for (int mt = 0; mt < 3; ++mt) {
        #pragma unroll
        for (int r = 0; r < 4; ++r) {
            int m = mt * 16 + lq * 4 + r;
            int p = m / 3;
            int i = m - p * 3;
            yb[p * 192 + i] = acc[mt][r];
        }
    }
}

extern "C" void kernel_launch(void* const* d_in, const int* in_sizes, int n_in,
                              void* d_out, int out_size, void* d_ws, size_t ws_size,
                              hipStream_t stream) {
    const float* X  = (const float*)d_in[0];
    const float* J  = (const float*)d_in[1];
    const float* A  = (const float*)d_in[2];
    const float* Bm = (const float*)d_in[3];
    const float* C  = (const float*)d_in[4];
    float* Y = (float*)d_out;

    const int points = in_sizes[0] / (64 * 3);   // B*N = 65536
    const int blocks = points / PTS;             // 4096
    affine_linear_fused<<<blocks, 256, 0, stream>>>(X, J, A, Bm, C, Y);
}